// Round 3
// baseline (1458.374 us; speedup 1.0000x reference)
//
#include <hip/hip_runtime.h>

// RNN_16492674416646: h_t = tanh(x_t W_ih^T + b_ih + b_hh + h_{t-1} W_hh^T),
// out_t = h_t W_out^T + b_out. T=2048, B=128, IN=2, H=200, OUT=1, fp32.
//
// One block per batch element (128 blocks, 512 threads = 8 waves).
// R3 structure: wave s in [0,8) owns k-slice [25s,25s+25); lane g owns rows
// 4g..4g+3 (g<50). h broadcast: ONE cooperative ds_read_b32 per wave + 25
// v_readlane -> h slice in SGPRs -> FMA with scalar operand. Kills R2's
// 160 ds_read_b128/step. Weights (100 floats/thread) pinned into VGPRs with
// empty asm so the compiler cannot rematerialize the loads inside the t-loop
// (R2 failure mode: VGPR_Count=40, per-step W_hh re-fetch).

static constexpr int T = 2048;
static constexpr int B = 128;
static constexpr int H = 200;
static constexpr int KS = 25;     // k-slice width per wave
static constexpr int S  = 8;      // slices = waves
static constexpr int R  = 4;      // rows per lane
static constexpr int NTHR = 512;

__global__ __launch_bounds__(NTHR, 2)
void rnn_fused(const float* __restrict__ x,     // [T,B,2]
               const float* __restrict__ W_ih,  // [H,2]
               const float* __restrict__ W_hh,  // [H,H]
               const float* __restrict__ b_ih,  // [H]
               const float* __restrict__ b_hh,  // [H]
               const float* __restrict__ W_out, // [1,H]
               const float* __restrict__ b_out, // [1]
               float* __restrict__ out)         // [T,B]
{
    const int b    = blockIdx.x;
    const int tid  = threadIdx.x;
    const int s    = tid >> 6;         // wave id = k-slice id
    const int lane = tid & 63;
    const bool rowact = (lane < 50);   // lane g owns rows 4g..4g+3
    const int g    = rowact ? lane : 49;  // clamp for safe loads
    const int j0   = R * g;
    const int k0   = KS * s;

    __shared__ float hbuf[H];          // current hidden state
    __shared__ float part[S][H];       // per-slice partials
    __shared__ float headv[256];       // h*W_out products (tail zeroed)
    __shared__ float xs[2 * T];        // this block's x column (16 KB)

    // --- one-time: weights into registers, then PIN so they stay there ---
    float wreg[R][KS];
#pragma unroll
    for (int r = 0; r < R; ++r)
#pragma unroll
        for (int i = 0; i < KS; ++i)
            wreg[r][i] = W_hh[(j0 + r) * H + k0 + i];
#pragma unroll
    for (int r = 0; r < R; ++r)
#pragma unroll
        for (int i = 0; i < KS; ++i)
            asm volatile("" : "+v"(wreg[r][i]));   // opaque: no remat, no sink

    // --- one-time: stage x[:, b, :] into LDS ---
    for (int idx = tid; idx < T; idx += NTHR) {
        const float2 v = *(const float2*)(x + (size_t)idx * (B * 2) + 2 * b);
        xs[2 * idx + 0] = v.x;
        xs[2 * idx + 1] = v.y;
    }

    // --- one-time: phase-2 per-row constants (threads 0..199 own row tid) ---
    float wih0 = 0.f, wih1 = 0.f, bias = 0.f, wout = 0.f;
    if (tid < H) {
        wih0 = W_ih[tid * 2 + 0];
        wih1 = W_ih[tid * 2 + 1];
        bias = b_ih[tid] + b_hh[tid];
        wout = W_out[tid];
    }
    const float bo = b_out[0];

    if (tid < H) hbuf[tid] = 0.f;      // h_0 = 0
    if (tid < 256) headv[tid] = 0.f;
    __syncthreads();

    float* op = out + b;

    for (int t = 0; t < T; ++t) {
        // --- phase 1: cooperative h-slice read + SGPR broadcast + FMA ---
        const int hidx = (lane < KS) ? lane : 0;   // lanes >=25 duplicate
        const float hval = hbuf[k0 + hidx];        // ONE ds_read_b32 per wave

        float a0 = 0.f, a1 = 0.f, a2 = 0.f, a3 = 0.f;
#pragma unroll
        for (int i = 0; i < KS; ++i) {
            const float hs = __int_as_float(
                __builtin_amdgcn_readlane(__float_as_int(hval), i));  // SGPR
            a0 = fmaf(wreg[0][i], hs, a0);
            a1 = fmaf(wreg[1][i], hs, a1);
            a2 = fmaf(wreg[2][i], hs, a2);
            a3 = fmaf(wreg[3][i], hs, a3);
        }
        if (rowact) {
            float4 v; v.x = a0; v.y = a1; v.z = a2; v.w = a3;
            *(float4*)&part[s][j0] = v;            // ds_write_b128, conflict-free
        }
        __syncthreads();

        // --- phase 2: reduce 8 slices, input proj, tanh, stage head terms ---
        if (tid < H) {
            float sum = part[0][tid] + part[1][tid] + part[2][tid]
                      + part[3][tid] + part[4][tid] + part[5][tid]
                      + part[6][tid] + part[7][tid];
            const float x0 = xs[2 * t + 0];
            const float x1 = xs[2 * t + 1];
            const float pre = sum + fmaf(x0, wih0, fmaf(x1, wih1, bias));
            // tanh(x) = 1 - 2/(e^{2x}+1); saturates correctly at +-inf
            const float e  = __expf(2.f * pre);
            const float th = 1.f - 2.f / (e + 1.f);
            hbuf[tid]  = th;
            headv[tid] = th * wout;
        }
        __syncthreads();

        // --- head: out[t,b] = sum_j h[j]*W_out[j] + b_out, wave 0 only ---
        // (overlaps next step's phase 1 on the other 7 waves)
        if (tid < 64) {
            float v = headv[tid] + headv[tid + 64] + headv[tid + 128]
                    + ((tid + 192) < H ? headv[tid + 192] : 0.f);
#pragma unroll
            for (int off = 32; off > 0; off >>= 1)
                v += __shfl_down(v, off, 64);
            if (tid == 0) op[(size_t)t * B] = v + bo;
        }
    }
}

extern "C" void kernel_launch(void* const* d_in, const int* in_sizes, int n_in,
                              void* d_out, int out_size, void* d_ws, size_t ws_size,
                              hipStream_t stream) {
    const float* x     = (const float*)d_in[0];
    const float* W_ih  = (const float*)d_in[1];
    const float* W_hh  = (const float*)d_in[2];
    const float* b_ih  = (const float*)d_in[3];
    const float* b_hh  = (const float*)d_in[4];
    const float* W_out = (const float*)d_in[5];
    const float* b_out = (const float*)d_in[6];
    float* out = (float*)d_out;

    rnn_fused<<<B, NTHR, 0, stream>>>(x, W_ih, W_hh, b_ih, b_hh, W_out, b_out, out);
}